// Round 1
// baseline (675.906 us; speedup 1.0000x reference)
//
#include <hip/hip_runtime.h>

#define NN 8192
#define DD 128

// ---------------------------------------------------------------------------
// Kernel 1: sim = X @ X^T, fp32, 64x64 tile per block, full K=128 in LDS.
// A-tile stored row-major [64][128] (reads are wave-broadcast -> no conflict).
// B-tile stored transposed [128][64] (k-major) so each thread reads its 4
// consecutive output columns as one ds_read_b128; lanes are 2-way bank
// aliased (free on CDNA4).
// Output written to simOut (= grad half of d_out, used as scratch).
// ---------------------------------------------------------------------------
__global__ __launch_bounds__(256) void sim_kernel(const float* __restrict__ X,
                                                  float* __restrict__ simOut) {
  __shared__ float As[64 * 128];   // [i][k]
  __shared__ float Bs[128 * 64];   // [k][j]
  const int tid = threadIdx.x;
  const int i0 = blockIdx.y << 6;
  const int j0 = blockIdx.x << 6;

  // Stage A coalesced: rows i0..i0+63 are contiguous in X.
  for (int f = tid * 4; f < 64 * 128; f += 256 * 4) {
    *(float4*)&As[f] = *(const float4*)&X[(size_t)i0 * DD + f];
  }
  // Stage B transposed: thread t handles row r = t&63, quarter dq = t>>6.
  {
    const int r = tid & 63;
    const int dq = tid >> 6;
    const float* src = &X[(size_t)(j0 + r) * DD + dq * 32];
#pragma unroll
    for (int d = 0; d < 32; d += 4) {
      float4 v = *(const float4*)&src[d];
      const int dd = dq * 32 + d;
      Bs[(dd + 0) * 64 + r] = v.x;
      Bs[(dd + 1) * 64 + r] = v.y;
      Bs[(dd + 2) * 64 + r] = v.z;
      Bs[(dd + 3) * 64 + r] = v.w;
    }
  }
  __syncthreads();

  const int tr = tid >> 4;  // 0..15 -> rows tr + 16*m
  const int tc = tid & 15;  // 0..15 -> cols 4*tc + n (contiguous quad)
  float acc[4][4] = {};

#pragma unroll 8
  for (int k = 0; k < DD; k += 4) {
    float4 av[4], bv[4];
#pragma unroll
    for (int m = 0; m < 4; ++m)
      av[m] = *(const float4*)&As[(tr + 16 * m) * DD + k];
#pragma unroll
    for (int q = 0; q < 4; ++q)
      bv[q] = *(const float4*)&Bs[(k + q) * 64 + tc * 4];
#pragma unroll
    for (int m = 0; m < 4; ++m) {
      const float* a = (const float*)&av[m];
#pragma unroll
      for (int n = 0; n < 4; ++n) {
        float t = acc[m][n];
        t = fmaf(a[0], ((const float*)&bv[0])[n], t);
        t = fmaf(a[1], ((const float*)&bv[1])[n], t);
        t = fmaf(a[2], ((const float*)&bv[2])[n], t);
        t = fmaf(a[3], ((const float*)&bv[3])[n], t);
        acc[m][n] = t;
      }
    }
  }

#pragma unroll
  for (int m = 0; m < 4; ++m) {
    float4 v = make_float4(acc[m][0], acc[m][1], acc[m][2], acc[m][3]);
    *(float4*)&simOut[(size_t)(i0 + tr + 16 * m) * NN + (j0 + tc * 4)] = v;
  }
}

// ---------------------------------------------------------------------------
// Kernel 2: one block per row i.
//   stage sim row + targets(u8) in LDS
//   -> block-reduce min_pos / max_neg
//   -> block-reduce p_cnt / n_cnt
//   -> elementwise loss/grad epilogue; grad overwrites sim in place.
// NOTE: simG and gradG alias (intentional) -> no __restrict__ here.
// ---------------------------------------------------------------------------
__global__ __launch_bounds__(256) void row_kernel(const float* simG,
                                                  const int* __restrict__ tgt,
                                                  float* lossG,
                                                  float* gradG) {
  __shared__ float srow[NN];
  __shared__ unsigned char tg[NN];
  __shared__ float redA[256];
  __shared__ float redB[256];
  const int i = blockIdx.x;
  const int tid = threadIdx.x;
  const size_t rowOff = (size_t)i * NN;

  for (int b = tid * 4; b < NN; b += 1024) {
    *(float4*)&srow[b] = *(const float4*)&simG[rowOff + b];
    int4 t4 = *(const int4*)&tgt[b];
    tg[b + 0] = (unsigned char)t4.x;
    tg[b + 1] = (unsigned char)t4.y;
    tg[b + 2] = (unsigned char)t4.z;
    tg[b + 3] = (unsigned char)t4.w;
  }
  const unsigned char ti = (unsigned char)tgt[i];
  __syncthreads();

  // --- min positive / max negative ---
  float lmin = 1e30f, lmax = -1e30f;
  for (int j = tid; j < NN; j += 256) {
    float s = srow[j];
    if (tg[j] == ti) {
      if (s < 1.0f) lmin = fminf(lmin, s);
    } else {
      lmax = fmaxf(lmax, s);
    }
  }
  redA[tid] = lmin;
  redB[tid] = lmax;
  __syncthreads();
  for (int off = 128; off > 0; off >>= 1) {
    if (tid < off) {
      redA[tid] = fminf(redA[tid], redA[tid + off]);
      redB[tid] = fmaxf(redB[tid], redB[tid + off]);
    }
    __syncthreads();
  }
  const float minpos = redA[0];
  const float maxneg = redB[0];
  __syncthreads();

  // --- counts of kept positives / negatives ---
  float pc = 0.f, nc = 0.f;
  for (int j = tid; j < NN; j += 256) {
    float s = srow[j];
    if (tg[j] == ti) {
      if (s < 1.0f && (s - 0.1f) < maxneg) pc += 1.f;
    } else {
      if ((s + 0.1f) > minpos) nc += 1.f;
    }
  }
  redA[tid] = pc;
  redB[tid] = nc;
  __syncthreads();
  for (int off = 128; off > 0; off >>= 1) {
    if (tid < off) {
      redA[tid] += redA[tid + off];
      redB[tid] += redB[tid + off];
    }
    __syncthreads();
  }
  const float pcnt = redA[0];
  const float ncnt = redB[0];
  const bool valid = (pcnt >= 1.f) && (ncnt >= 1.f);
  const float cp = -2.f / fmaxf(pcnt, 1.f);
  const float cn = 2.f / fmaxf(ncnt, 1.f);

  if (!valid) {
    const float4 z = make_float4(0.f, 0.f, 0.f, 0.f);
    for (int b = tid * 4; b < NN; b += 1024) {
      *(float4*)&lossG[rowOff + b] = z;
      *(float4*)&gradG[rowOff + b] = z;
    }
    return;
  }

  // --- elementwise loss / grad ---
  for (int b = tid * 4; b < NN; b += 1024) {
    float4 sv = *(const float4*)&srow[b];
    const float* sp = (const float*)&sv;
    float l[4], g[4];
#pragma unroll
    for (int e = 0; e < 4; ++e) {
      float s = sp[e];
      float lv = 0.f, gv = 0.f;
      if (tg[b + e] == ti) {
        if (s < 1.0f && (s - 0.1f) < maxneg) {
          // pos: z = -beta*(s-m) = -2(s-0.5)
          float ez = expf(-2.0f * (s - 0.5f));
          lv = log1pf(ez);              // (2/beta)=1
          gv = cp * (ez / (1.f + ez));  // -(2/P)*sigmoid(z)
        }
      } else {
        if ((s + 0.1f) > minpos) {
          // neg: z = alpha*(s-m) = 40(s-0.5); exp(z) <= exp(20), finite
          float ez = expf(40.0f * (s - 0.5f));
          lv = 0.05f * log1pf(ez);      // (2/alpha)=0.05
          gv = cn * (ez / (1.f + ez));  // (2/Nc)*sigmoid(z)
        }
      }
      l[e] = lv;
      g[e] = gv;
    }
    *(float4*)&lossG[rowOff + b] = make_float4(l[0], l[1], l[2], l[3]);
    *(float4*)&gradG[rowOff + b] = make_float4(g[0], g[1], g[2], g[3]);
  }
}

extern "C" void kernel_launch(void* const* d_in, const int* in_sizes, int n_in,
                              void* d_out, int out_size, void* d_ws,
                              size_t ws_size, hipStream_t stream) {
  const float* X = (const float*)d_in[0];
  const int* tgt = (const int*)d_in[1];
  float* out = (float*)d_out;
  float* lossG = out;                       // first N*N: pair_loss
  float* gradG = out + (size_t)NN * NN;     // second N*N: pair_grad (sim scratch)

  dim3 gA(NN / 64, NN / 64);
  hipLaunchKernelGGL(sim_kernel, gA, dim3(256), 0, stream, X, gradG);
  hipLaunchKernelGGL(row_kernel, dim3(NN), dim3(256), 0, stream, gradG, tgt,
                     lossG, gradG);
}

// Round 2
// 454.330 us; speedup vs baseline: 1.4877x; 1.4877x over previous
//
#include <hip/hip_runtime.h>

#define NN 8192
#define DD 128

// ---------------------------------------------------------------------------
// Kernel 1: sim = X @ X^T, fp32, 64x64 tile, full K=128 in LDS.
// Symmetry: only blocks with bj >= bi compute; off-diagonal blocks also write
// the mirrored tile via an LDS transpose (sim is exactly symmetric under our
// fixed fma order, so mirrored values are bit-identical to direct compute).
// ---------------------------------------------------------------------------
__global__ __launch_bounds__(256) void sim_kernel(const float* __restrict__ X,
                                                  float* __restrict__ simOut) {
  if (blockIdx.x < blockIdx.y) return;  // uniform early exit (lower triangle)
  __shared__ float As[64 * 128];   // [i][k]  (reused as transpose buffer)
  __shared__ float Bs[128 * 64];   // [k][j]
  const int tid = threadIdx.x;
  const int i0 = blockIdx.y << 6;
  const int j0 = blockIdx.x << 6;

  // Stage A coalesced: rows i0..i0+63 are contiguous in X.
  for (int f = tid * 4; f < 64 * 128; f += 256 * 4) {
    *(float4*)&As[f] = *(const float4*)&X[(size_t)i0 * DD + f];
  }
  // Stage B transposed: thread t handles row r = t&63, quarter dq = t>>6.
  {
    const int r = tid & 63;
    const int dq = tid >> 6;
    const float* src = &X[(size_t)(j0 + r) * DD + dq * 32];
#pragma unroll
    for (int d = 0; d < 32; d += 4) {
      float4 v = *(const float4*)&src[d];
      const int dd = dq * 32 + d;
      Bs[(dd + 0) * 64 + r] = v.x;
      Bs[(dd + 1) * 64 + r] = v.y;
      Bs[(dd + 2) * 64 + r] = v.z;
      Bs[(dd + 3) * 64 + r] = v.w;
    }
  }
  __syncthreads();

  const int tr = tid >> 4;  // 0..15 -> rows tr + 16*m
  const int tc = tid & 15;  // 0..15 -> cols 4*tc + n (contiguous quad)
  float acc[4][4] = {};

#pragma unroll 8
  for (int k = 0; k < DD; k += 4) {
    float4 av[4], bv[4];
#pragma unroll
    for (int m = 0; m < 4; ++m)
      av[m] = *(const float4*)&As[(tr + 16 * m) * DD + k];
#pragma unroll
    for (int q = 0; q < 4; ++q)
      bv[q] = *(const float4*)&Bs[(k + q) * 64 + tc * 4];
#pragma unroll
    for (int m = 0; m < 4; ++m) {
      const float* a = (const float*)&av[m];
#pragma unroll
      for (int n = 0; n < 4; ++n) {
        float t = acc[m][n];
        t = fmaf(a[0], ((const float*)&bv[0])[n], t);
        t = fmaf(a[1], ((const float*)&bv[1])[n], t);
        t = fmaf(a[2], ((const float*)&bv[2])[n], t);
        t = fmaf(a[3], ((const float*)&bv[3])[n], t);
        acc[m][n] = t;
      }
    }
  }

  // Direct tile write.
#pragma unroll
  for (int m = 0; m < 4; ++m) {
    float4 v = make_float4(acc[m][0], acc[m][1], acc[m][2], acc[m][3]);
    *(float4*)&simOut[(size_t)(i0 + tr + 16 * m) * NN + (j0 + tc * 4)] = v;
  }

  if (blockIdx.x == blockIdx.y) return;  // uniform

  // Mirror tile via LDS transpose (reuse As region; padded stride 68 words).
  float* Ls = As;
  __syncthreads();  // all K-loop reads of As/Bs done
#pragma unroll
  for (int m = 0; m < 4; ++m) {
    const int r = tr + 16 * m;
    *(float4*)&Ls[r * 68 + tc * 4] =
        make_float4(acc[m][0], acc[m][1], acc[m][2], acc[m][3]);
  }
  __syncthreads();
  // Write mirrored tile: item idx -> (c = row of mirror, r4 = float4 col).
#pragma unroll
  for (int it = 0; it < 4; ++it) {
    const int r4 = tid & 15;
    const int c = (tid >> 4) + 16 * it;
    float4 v;
    v.x = Ls[(r4 * 4 + 0) * 68 + c];
    v.y = Ls[(r4 * 4 + 1) * 68 + c];
    v.z = Ls[(r4 * 4 + 2) * 68 + c];
    v.w = Ls[(r4 * 4 + 3) * 68 + c];
    *(float4*)&simOut[(size_t)(j0 + c) * NN + (i0 + r4 * 4)] = v;
  }
}

// ---------------------------------------------------------------------------
// Kernel 2: one block (256 threads) per row i. Each thread holds its 32 sim
// values in registers (8 x float4). Targets staged as u8 in LDS. Branchless
// passes; native transcendentals (__expf/__logf/__fdividef).
// NOTE: simG and gradG alias (grad overwrites sim in place).
// ---------------------------------------------------------------------------
__global__ __launch_bounds__(256) void row_kernel(const float* simG,
                                                  const int* __restrict__ tgt,
                                                  float* lossG,
                                                  float* gradG) {
  __shared__ unsigned char tg[NN];
  __shared__ float redA[4];
  __shared__ float redB[4];
  const int i = blockIdx.x;
  const int tid = threadIdx.x;
  const size_t rowOff = (size_t)i * NN;

  // Stage targets as u8.
  for (int b = tid * 4; b < NN; b += 1024) {
    int4 t4 = *(const int4*)&tgt[b];
    tg[b + 0] = (unsigned char)t4.x;
    tg[b + 1] = (unsigned char)t4.y;
    tg[b + 2] = (unsigned char)t4.z;
    tg[b + 3] = (unsigned char)t4.w;
  }
  const unsigned char tci = (unsigned char)tgt[i];

  // Load this row into registers (coalesced b128).
  float4 sv[8];
#pragma unroll
  for (int q = 0; q < 8; ++q)
    sv[q] = *(const float4*)&simG[rowOff + (size_t)(tid * 4 + q * 1024)];
  __syncthreads();

  // --- pass 1: same-class mask + min positive / max negative ---
  unsigned mmask = 0;
  float lmin = 1e30f, lmax = -1e30f;
#pragma unroll
  for (int q = 0; q < 8; ++q) {
    uchar4 t4 = *(const uchar4*)&tg[tid * 4 + q * 1024];
    const unsigned char tt[4] = {t4.x, t4.y, t4.z, t4.w};
    const float* sp = (const float*)&sv[q];
#pragma unroll
    for (int e = 0; e < 4; ++e) {
      const bool same = (tt[e] == tci);
      const float s = sp[e];
      if (same) {
        mmask |= (1u << (q * 4 + e));
        if (s < 1.0f) lmin = fminf(lmin, s);
      } else {
        lmax = fmaxf(lmax, s);
      }
    }
  }
#pragma unroll
  for (int off = 32; off > 0; off >>= 1) {
    lmin = fminf(lmin, __shfl_down(lmin, off));
    lmax = fmaxf(lmax, __shfl_down(lmax, off));
  }
  if ((tid & 63) == 0) {
    redA[tid >> 6] = lmin;
    redB[tid >> 6] = lmax;
  }
  __syncthreads();
  const float minpos = fminf(fminf(redA[0], redA[1]), fminf(redA[2], redA[3]));
  const float maxneg = fmaxf(fmaxf(redB[0], redB[1]), fmaxf(redB[2], redB[3]));
  __syncthreads();  // before red reuse

  // --- pass 2: counts of kept positives / negatives ---
  float pc = 0.f, nc = 0.f;
#pragma unroll
  for (int q = 0; q < 8; ++q) {
    const float* sp = (const float*)&sv[q];
#pragma unroll
    for (int e = 0; e < 4; ++e) {
      const bool same = (mmask >> (q * 4 + e)) & 1u;
      const float s = sp[e];
      if (same) {
        if (s < 1.0f && (s - 0.1f) < maxneg) pc += 1.f;
      } else {
        if ((s + 0.1f) > minpos) nc += 1.f;
      }
    }
  }
#pragma unroll
  for (int off = 32; off > 0; off >>= 1) {
    pc += __shfl_down(pc, off);
    nc += __shfl_down(nc, off);
  }
  if ((tid & 63) == 0) {
    redA[tid >> 6] = pc;
    redB[tid >> 6] = nc;
  }
  __syncthreads();
  const float pcnt = redA[0] + redA[1] + redA[2] + redA[3];
  const float ncnt = redB[0] + redB[1] + redB[2] + redB[3];
  const bool valid = (pcnt >= 1.f) && (ncnt >= 1.f);
  const float cp = -2.f / fmaxf(pcnt, 1.f);
  const float cn = 2.f / fmaxf(ncnt, 1.f);

  // --- pass 3: loss / grad epilogue (branchless, native transcendentals) ---
#pragma unroll
  for (int q = 0; q < 8; ++q) {
    const float* sp = (const float*)&sv[q];
    float lo[4], go[4];
#pragma unroll
    for (int e = 0; e < 4; ++e) {
      const float s = sp[e];
      const bool same = (mmask >> (q * 4 + e)) & 1u;
      bool keep = same ? (s < 1.0f && (s - 0.1f) < maxneg)
                       : ((s + 0.1f) > minpos);
      keep = keep && valid;
      // z = -2(s-0.5) for positives, 40(s-0.5) for negatives; |z| <= ~20.2
      const float z = same ? fmaf(-2.f, s, 1.f) : fmaf(40.f, s, -20.f);
      const float ez = __expf(z);
      const float d = 1.f + ez;
      const float ll = __logf(d);              // log1p(e^z)
      const float sig = __fdividef(ez, d);     // sigmoid(z)
      const float lv = same ? ll : 0.05f * ll; // (2/beta)=1, (2/alpha)=0.05
      const float gv = (same ? cp : cn) * sig;
      lo[e] = keep ? lv : 0.f;
      go[e] = keep ? gv : 0.f;
    }
    const size_t a = rowOff + (size_t)(tid * 4 + q * 1024);
    *(float4*)&lossG[a] = make_float4(lo[0], lo[1], lo[2], lo[3]);
    *(float4*)&gradG[a] = make_float4(go[0], go[1], go[2], go[3]);
  }
}

extern "C" void kernel_launch(void* const* d_in, const int* in_sizes, int n_in,
                              void* d_out, int out_size, void* d_ws,
                              size_t ws_size, hipStream_t stream) {
  const float* X = (const float*)d_in[0];
  const int* tgt = (const int*)d_in[1];
  float* out = (float*)d_out;
  float* lossG = out;                    // first N*N: pair_loss
  float* gradG = out + (size_t)NN * NN;  // second N*N: pair_grad (sim scratch)

  dim3 gA(NN / 64, NN / 64);
  hipLaunchKernelGGL(sim_kernel, gA, dim3(256), 0, stream, X, gradG);
  hipLaunchKernelGGL(row_kernel, dim3(NN), dim3(256), 0, stream, gradG, tgt,
                     lossG, gradG);
}

// Round 3
// 436.782 us; speedup vs baseline: 1.5475x; 1.0402x over previous
//
#include <hip/hip_runtime.h>
#include <hip/hip_fp16.h>

#define NN 8192
#define DD 128

typedef _Float16 f16x8 __attribute__((ext_vector_type(8)));
typedef float f32x4 __attribute__((ext_vector_type(4)));

// ---------------------------------------------------------------------------
// prep: split X (fp32) into f16 hi/lo: x = h + l, |l| <= 2^-11 |x|.
// ---------------------------------------------------------------------------
__global__ __launch_bounds__(256) void prep_kernel(const float* __restrict__ X,
                                                   _Float16* __restrict__ Xh,
                                                   _Float16* __restrict__ Xl) {
  const int t = blockIdx.x * 256 + threadIdx.x;  // 8 elems per thread
  const size_t base = (size_t)t * 8;
  float4 a = *(const float4*)&X[base];
  float4 b = *(const float4*)&X[base + 4];
  const float av[8] = {a.x, a.y, a.z, a.w, b.x, b.y, b.z, b.w};
  f16x8 h, l;
#pragma unroll
  for (int e = 0; e < 8; ++e) {
    const _Float16 hh = (_Float16)av[e];
    h[e] = hh;
    l[e] = (_Float16)(av[e] - (float)hh);
  }
  *(f16x8*)&Xh[base] = h;
  *(f16x8*)&Xl[base] = l;
}

// ---------------------------------------------------------------------------
// sim = X @ X^T via split-f16 MFMA: Ah*Bh + Ah*Bl + Al*Bh.
// 64x64 tile per 256-thread block; wave w owns rows [w*16, w*16+16).
// mfma_f32_16x16x32_f16 fragment mapping: A row m = lane&15, k = (lane>>4)*8+e;
// B col n = lane&15, same k mapping -> both operands are contiguous 16B runs
// of row-major X; identical A/B k-mappings make the result immune to any
// k-permutation error. C/D: col = lane&15, row = (lane>>4)*4 + reg (m89).
// Epilogue: LDS transpose (stride 68 words -> 2-way = free) for float4 stores.
// ---------------------------------------------------------------------------
__global__ __launch_bounds__(256) void sim_mfma_kernel(
    const _Float16* __restrict__ Xh, const _Float16* __restrict__ Xl,
    float* __restrict__ simOut) {
  __shared__ float Ls[64 * 68];
  const int tid = threadIdx.x;
  const int w = tid >> 6, lane = tid & 63;
  const int i0 = blockIdx.y * 64, j0 = blockIdx.x * 64;
  const int m = lane & 15, kq = lane >> 4;
  const int koff = kq * 8;

  f32x4 acc[4] = {{0.f, 0.f, 0.f, 0.f},
                  {0.f, 0.f, 0.f, 0.f},
                  {0.f, 0.f, 0.f, 0.f},
                  {0.f, 0.f, 0.f, 0.f}};
  const _Float16* Ah_p = Xh + (size_t)(i0 + w * 16 + m) * DD + koff;
  const _Float16* Al_p = Xl + (size_t)(i0 + w * 16 + m) * DD + koff;

#pragma unroll
  for (int k0 = 0; k0 < 4; ++k0) {
    const f16x8 ah = *(const f16x8*)(Ah_p + k0 * 32);
    const f16x8 al = *(const f16x8*)(Al_p + k0 * 32);
#pragma unroll
    for (int ct = 0; ct < 4; ++ct) {
      const size_t boff = (size_t)(j0 + ct * 16 + m) * DD + koff + k0 * 32;
      const f16x8 bh = *(const f16x8*)(Xh + boff);
      const f16x8 bl = *(const f16x8*)(Xl + boff);
      acc[ct] = __builtin_amdgcn_mfma_f32_16x16x32_f16(ah, bh, acc[ct], 0, 0, 0);
      acc[ct] = __builtin_amdgcn_mfma_f32_16x16x32_f16(ah, bl, acc[ct], 0, 0, 0);
      acc[ct] = __builtin_amdgcn_mfma_f32_16x16x32_f16(al, bh, acc[ct], 0, 0, 0);
    }
  }

  // acc -> LDS (C/D layout), then coalesced float4 stores.
#pragma unroll
  for (int ct = 0; ct < 4; ++ct)
#pragma unroll
    for (int r = 0; r < 4; ++r)
      Ls[(w * 16 + kq * 4 + r) * 68 + ct * 16 + m] = acc[ct][r];
  __syncthreads();
  const int fr = tid & 15, r0 = tid >> 4;
#pragma unroll
  for (int it = 0; it < 4; ++it) {
    const int row = r0 + 16 * it;
    const float4 v = *(const float4*)&Ls[row * 68 + fr * 4];
    *(float4*)&simOut[(size_t)(i0 + row) * NN + j0 + fr * 4] = v;
  }
}

// ---------------------------------------------------------------------------
// Fallback fp32 sim (round-1 kernel) if d_ws is too small for Xh/Xl.
// ---------------------------------------------------------------------------
__global__ __launch_bounds__(256) void sim_fp32_kernel(
    const float* __restrict__ X, float* __restrict__ simOut) {
  __shared__ float As[64 * 128];
  __shared__ float Bs[128 * 64];
  const int tid = threadIdx.x;
  const int i0 = blockIdx.y << 6;
  const int j0 = blockIdx.x << 6;
  for (int f = tid * 4; f < 64 * 128; f += 256 * 4)
    *(float4*)&As[f] = *(const float4*)&X[(size_t)i0 * DD + f];
  {
    const int r = tid & 63;
    const int dq = tid >> 6;
    const float* src = &X[(size_t)(j0 + r) * DD + dq * 32];
#pragma unroll
    for (int d = 0; d < 32; d += 4) {
      float4 v = *(const float4*)&src[d];
      const int dd = dq * 32 + d;
      Bs[(dd + 0) * 64 + r] = v.x;
      Bs[(dd + 1) * 64 + r] = v.y;
      Bs[(dd + 2) * 64 + r] = v.z;
      Bs[(dd + 3) * 64 + r] = v.w;
    }
  }
  __syncthreads();
  const int tr = tid >> 4;
  const int tc = tid & 15;
  float acc[4][4] = {};
#pragma unroll 8
  for (int k = 0; k < DD; k += 4) {
    float4 av[4], bv[4];
#pragma unroll
    for (int mm = 0; mm < 4; ++mm)
      av[mm] = *(const float4*)&As[(tr + 16 * mm) * DD + k];
#pragma unroll
    for (int q = 0; q < 4; ++q)
      bv[q] = *(const float4*)&Bs[(k + q) * 64 + tc * 4];
#pragma unroll
    for (int mm = 0; mm < 4; ++mm) {
      const float* a = (const float*)&av[mm];
#pragma unroll
      for (int n = 0; n < 4; ++n) {
        float t = acc[mm][n];
        t = fmaf(a[0], ((const float*)&bv[0])[n], t);
        t = fmaf(a[1], ((const float*)&bv[1])[n], t);
        t = fmaf(a[2], ((const float*)&bv[2])[n], t);
        t = fmaf(a[3], ((const float*)&bv[3])[n], t);
        acc[mm][n] = t;
      }
    }
  }
#pragma unroll
  for (int mm = 0; mm < 4; ++mm) {
    float4 v = make_float4(acc[mm][0], acc[mm][1], acc[mm][2], acc[mm][3]);
    *(float4*)&simOut[(size_t)(i0 + tr + 16 * mm) * NN + (j0 + tc * 4)] = v;
  }
}

// ---------------------------------------------------------------------------
// row_kernel: one block per row; 32 sim values per thread in registers,
// native transcendentals, branchless epilogue. (unchanged, at memory floor)
// ---------------------------------------------------------------------------
__global__ __launch_bounds__(256) void row_kernel(const float* simG,
                                                  const int* __restrict__ tgt,
                                                  float* lossG,
                                                  float* gradG) {
  __shared__ unsigned char tg[NN];
  __shared__ float redA[4];
  __shared__ float redB[4];
  const int i = blockIdx.x;
  const int tid = threadIdx.x;
  const size_t rowOff = (size_t)i * NN;

  for (int b = tid * 4; b < NN; b += 1024) {
    int4 t4 = *(const int4*)&tgt[b];
    tg[b + 0] = (unsigned char)t4.x;
    tg[b + 1] = (unsigned char)t4.y;
    tg[b + 2] = (unsigned char)t4.z;
    tg[b + 3] = (unsigned char)t4.w;
  }
  const unsigned char tci = (unsigned char)tgt[i];

  float4 sv[8];
#pragma unroll
  for (int q = 0; q < 8; ++q)
    sv[q] = *(const float4*)&simG[rowOff + (size_t)(tid * 4 + q * 1024)];
  __syncthreads();

  unsigned mmask = 0;
  float lmin = 1e30f, lmax = -1e30f;
#pragma unroll
  for (int q = 0; q < 8; ++q) {
    uchar4 t4 = *(const uchar4*)&tg[tid * 4 + q * 1024];
    const unsigned char tt[4] = {t4.x, t4.y, t4.z, t4.w};
    const float* sp = (const float*)&sv[q];
#pragma unroll
    for (int e = 0; e < 4; ++e) {
      const bool same = (tt[e] == tci);
      const float s = sp[e];
      if (same) {
        mmask |= (1u << (q * 4 + e));
        if (s < 1.0f) lmin = fminf(lmin, s);
      } else {
        lmax = fmaxf(lmax, s);
      }
    }
  }
#pragma unroll
  for (int off = 32; off > 0; off >>= 1) {
    lmin = fminf(lmin, __shfl_down(lmin, off));
    lmax = fmaxf(lmax, __shfl_down(lmax, off));
  }
  if ((tid & 63) == 0) {
    redA[tid >> 6] = lmin;
    redB[tid >> 6] = lmax;
  }
  __syncthreads();
  const float minpos = fminf(fminf(redA[0], redA[1]), fminf(redA[2], redA[3]));
  const float maxneg = fmaxf(fmaxf(redB[0], redB[1]), fmaxf(redB[2], redB[3]));
  __syncthreads();

  float pc = 0.f, nc = 0.f;
#pragma unroll
  for (int q = 0; q < 8; ++q) {
    const float* sp = (const float*)&sv[q];
#pragma unroll
    for (int e = 0; e < 4; ++e) {
      const bool same = (mmask >> (q * 4 + e)) & 1u;
      const float s = sp[e];
      if (same) {
        if (s < 1.0f && (s - 0.1f) < maxneg) pc += 1.f;
      } else {
        if ((s + 0.1f) > minpos) nc += 1.f;
      }
    }
  }
#pragma unroll
  for (int off = 32; off > 0; off >>= 1) {
    pc += __shfl_down(pc, off);
    nc += __shfl_down(nc, off);
  }
  if ((tid & 63) == 0) {
    redA[tid >> 6] = pc;
    redB[tid >> 6] = nc;
  }
  __syncthreads();
  const float pcnt = redA[0] + redA[1] + redA[2] + redA[3];
  const float ncnt = redB[0] + redB[1] + redB[2] + redB[3];
  const bool valid = (pcnt >= 1.f) && (ncnt >= 1.f);
  const float cp = -2.f / fmaxf(pcnt, 1.f);
  const float cn = 2.f / fmaxf(ncnt, 1.f);

#pragma unroll
  for (int q = 0; q < 8; ++q) {
    const float* sp = (const float*)&sv[q];
    float lo[4], go[4];
#pragma unroll
    for (int e = 0; e < 4; ++e) {
      const float s = sp[e];
      const bool same = (mmask >> (q * 4 + e)) & 1u;
      bool keep = same ? (s < 1.0f && (s - 0.1f) < maxneg)
                       : ((s + 0.1f) > minpos);
      keep = keep && valid;
      const float z = same ? fmaf(-2.f, s, 1.f) : fmaf(40.f, s, -20.f);
      const float ez = __expf(z);
      const float d = 1.f + ez;
      const float ll = __logf(d);
      const float sig = __fdividef(ez, d);
      const float lv = same ? ll : 0.05f * ll;
      const float gv = (same ? cp : cn) * sig;
      lo[e] = keep ? lv : 0.f;
      go[e] = keep ? gv : 0.f;
    }
    const size_t a = rowOff + (size_t)(tid * 4 + q * 1024);
    *(float4*)&lossG[a] = make_float4(lo[0], lo[1], lo[2], lo[3]);
    *(float4*)&gradG[a] = make_float4(go[0], go[1], go[2], go[3]);
  }
}

extern "C" void kernel_launch(void* const* d_in, const int* in_sizes, int n_in,
                              void* d_out, int out_size, void* d_ws,
                              size_t ws_size, hipStream_t stream) {
  const float* X = (const float*)d_in[0];
  const int* tgt = (const int*)d_in[1];
  float* out = (float*)d_out;
  float* lossG = out;                    // first N*N: pair_loss
  float* gradG = out + (size_t)NN * NN;  // second N*N: pair_grad (sim scratch)

  const size_t xbytes = (size_t)NN * DD * sizeof(_Float16);  // 2 MiB
  if (ws_size >= 2 * xbytes) {
    _Float16* Xh = (_Float16*)d_ws;
    _Float16* Xl = (_Float16*)((char*)d_ws + xbytes);
    hipLaunchKernelGGL(prep_kernel, dim3(NN * DD / (256 * 8)), dim3(256), 0,
                       stream, X, Xh, Xl);
    hipLaunchKernelGGL(sim_mfma_kernel, dim3(NN / 64, NN / 64), dim3(256), 0,
                       stream, Xh, Xl, gradG);
  } else {
    hipLaunchKernelGGL(sim_fp32_kernel, dim3(NN / 64, NN / 64), dim3(256), 0,
                       stream, X, gradG);
  }
  hipLaunchKernelGGL(row_kernel, dim3(NN), dim3(256), 0, stream, gradG, tgt,
                     lossG, gradG);
}

// Round 4
// 239.546 us; speedup vs baseline: 2.8216x; 1.8234x over previous
//
#include <hip/hip_runtime.h>
#include <hip/hip_fp16.h>

#define NN 8192
#define DD 128

typedef _Float16 f16x8 __attribute__((ext_vector_type(8)));
typedef float f32x4 __attribute__((ext_vector_type(4)));

// ---------------------------------------------------------------------------
// prep: Xc[row][0..127] = f16(x), Xc[row][128..255] = f16(x - f16(x)).
// sim = Xc @ Xc^T then equals x@x^T up to ~1e-6 (hi*hi + hi*lo + lo*hi + lo*lo).
// ---------------------------------------------------------------------------
__global__ __launch_bounds__(256) void prep_kernel(const float* __restrict__ X,
                                                   _Float16* __restrict__ Xc) {
  const int t = blockIdx.x * 256 + threadIdx.x;  // 8 elems per thread
  const size_t base = (size_t)t * 8;
  const int row = (int)(base >> 7);
  const int col = (int)(base & 127);
  float4 a = *(const float4*)&X[base];
  float4 b = *(const float4*)&X[base + 4];
  const float av[8] = {a.x, a.y, a.z, a.w, b.x, b.y, b.z, b.w};
  f16x8 h, l;
#pragma unroll
  for (int e = 0; e < 8; ++e) {
    const _Float16 hh = (_Float16)av[e];
    h[e] = hh;
    l[e] = (_Float16)(av[e] - (float)hh);
  }
  *(f16x8*)&Xc[(size_t)row * 256 + col] = h;
  *(f16x8*)&Xc[(size_t)row * 256 + 128 + col] = l;
}

// ---------------------------------------------------------------------------
// sim = Xc @ Xc^T, M=N=8192, K=256 f16. 128x128 tile, 512 thr (8 waves 2x4),
// BK=128 (2 K-steps). LDS-staged via global_load_lds width-16 with XOR
// swizzle (chunk ^= row&15 within the 256B row) applied on BOTH the global
// source and the ds_read address -> bank-balanced ds_read_b128.
// Fragment k-permutation immunity: A and B frags use the identical
// (row-class, lane, t) -> address formula, so any within-slab k-permutation
// cancels in A.B^T.  C/D layout per m89: col=lane&15, row=(lane>>4)*4+reg.
// Epilogue: LDS transpose (stride 132 f32) -> coalesced float4 stores.
// ---------------------------------------------------------------------------
__global__ __launch_bounds__(512) void sim_mfma_kernel(
    const _Float16* __restrict__ Xc, float* __restrict__ simOut) {
  __shared__ char smem[65536];
  _Float16* As = (_Float16*)smem;            // 32 KB: rows i0..i0+127, 128 k
  _Float16* Bs = (_Float16*)(smem + 32768);  // 32 KB: rows j0..j0+127, 128 k

  // bijective XCD swizzle (4096 % 8 == 0)
  const int flat = blockIdx.x;
  const int swz = (flat & 7) * 512 + (flat >> 3);
  const int i0 = (swz >> 6) << 7;  // tile row
  const int j0 = (swz & 63) << 7;  // tile col

  const int tid = threadIdx.x;
  const int lane = tid & 63;
  const int w = tid >> 6;
  const int m = lane & 15, kq = lane >> 4;
  const int wr = w >> 2, wc = w & 3;  // wave owns rows wr*64+.., cols wc*32+..

  f32x4 acc[4][2] = {};

#pragma unroll
  for (int ks = 0; ks < 2; ++ks) {
    if (ks) __syncthreads();  // prior K-step's ds_reads done before overwrite
    // stage A and B tiles: 2048 chunks of 16B each; 4 per thread per tile.
#pragma unroll
    for (int it = 0; it < 4; ++it) {
      const int C = it * 512 + tid;   // = uniform(it,w)*... + lane -> OK for lds dest
      const int r = C >> 4;
      const int k = C & 15;
      const int kk = k ^ (r & 15);    // inverse swizzle on the global source
      const char* ga = (const char*)Xc + (((size_t)(i0 + r)) << 9) + ks * 256 + (kk << 4);
      const char* gb = (const char*)Xc + (((size_t)(j0 + r)) << 9) + ks * 256 + (kk << 4);
      __builtin_amdgcn_global_load_lds(
          (const __attribute__((address_space(1))) void*)ga,
          (__attribute__((address_space(3))) void*)(smem + C * 16), 16, 0, 0);
      __builtin_amdgcn_global_load_lds(
          (const __attribute__((address_space(1))) void*)gb,
          (__attribute__((address_space(3))) void*)(smem + 32768 + C * 16), 16, 0, 0);
    }
    __syncthreads();  // compiler drains vmcnt before s_barrier

#pragma unroll
    for (int t = 0; t < 4; ++t) {
      const int ch = (t * 4 + kq) ^ m;  // swizzled chunk for this lane's rows
      f16x8 af[4], bf[2];
#pragma unroll
      for (int f = 0; f < 4; ++f) {
        const int R = wr * 64 + f * 16 + m;  // R&15 == m
        af[f] = *(const f16x8*)(As + R * 128 + ch * 8);
      }
#pragma unroll
      for (int g = 0; g < 2; ++g) {
        const int R = wc * 32 + g * 16 + m;  // R&15 == m
        bf[g] = *(const f16x8*)(Bs + R * 128 + ch * 8);
      }
#pragma unroll
      for (int f = 0; f < 4; ++f)
#pragma unroll
        for (int g = 0; g < 2; ++g)
          acc[f][g] =
              __builtin_amdgcn_mfma_f32_16x16x32_f16(af[f], bf[g], acc[f][g], 0, 0, 0);
    }
  }
  __syncthreads();  // last K-step's ds_reads done; LDS now free for epilogue

  // Epilogue: half-tile (64 rows) at a time through LDS, float4 stores.
  float* Tr = (float*)smem;  // 64 x 132 f32 = 33.8 KB
#pragma unroll
  for (int ph = 0; ph < 2; ++ph) {
    if (ph) __syncthreads();
    if (wr == ph) {
#pragma unroll
      for (int f = 0; f < 4; ++f)
#pragma unroll
        for (int g = 0; g < 2; ++g)
#pragma unroll
          for (int rg = 0; rg < 4; ++rg)
            Tr[(f * 16 + kq * 4 + rg) * 132 + wc * 32 + g * 16 + m] = acc[f][g][rg];
    }
    __syncthreads();
#pragma unroll
    for (int it = 0; it < 4; ++it) {
      const int F = it * 512 + tid;
      const int row = F >> 5;
      const int c4 = (F & 31) * 4;
      const float4 v = *(const float4*)&Tr[row * 132 + c4];
      *(float4*)&simOut[(size_t)(i0 + ph * 64 + row) * NN + j0 + c4] = v;
    }
  }
}

// ---------------------------------------------------------------------------
// row_kernel: one block per row; 32 sim values per thread in registers,
// native transcendentals, branchless epilogue. (at memory floor, unchanged)
// ---------------------------------------------------------------------------
__global__ __launch_bounds__(256) void row_kernel(const float* simG,
                                                  const int* __restrict__ tgt,
                                                  float* lossG,
                                                  float* gradG) {
  __shared__ unsigned char tg[NN];
  __shared__ float redA[4];
  __shared__ float redB[4];
  const int i = blockIdx.x;
  const int tid = threadIdx.x;
  const size_t rowOff = (size_t)i * NN;

  for (int b = tid * 4; b < NN; b += 1024) {
    int4 t4 = *(const int4*)&tgt[b];
    tg[b + 0] = (unsigned char)t4.x;
    tg[b + 1] = (unsigned char)t4.y;
    tg[b + 2] = (unsigned char)t4.z;
    tg[b + 3] = (unsigned char)t4.w;
  }
  const unsigned char tci = (unsigned char)tgt[i];

  float4 sv[8];
#pragma unroll
  for (int q = 0; q < 8; ++q)
    sv[q] = *(const float4*)&simG[rowOff + (size_t)(tid * 4 + q * 1024)];
  __syncthreads();

  unsigned mmask = 0;
  float lmin = 1e30f, lmax = -1e30f;
#pragma unroll
  for (int q = 0; q < 8; ++q) {
    uchar4 t4 = *(const uchar4*)&tg[tid * 4 + q * 1024];
    const unsigned char tt[4] = {t4.x, t4.y, t4.z, t4.w};
    const float* sp = (const float*)&sv[q];
#pragma unroll
    for (int e = 0; e < 4; ++e) {
      const bool same = (tt[e] == tci);
      const float s = sp[e];
      if (same) {
        mmask |= (1u << (q * 4 + e));
        if (s < 1.0f) lmin = fminf(lmin, s);
      } else {
        lmax = fmaxf(lmax, s);
      }
    }
  }
#pragma unroll
  for (int off = 32; off > 0; off >>= 1) {
    lmin = fminf(lmin, __shfl_down(lmin, off));
    lmax = fmaxf(lmax, __shfl_down(lmax, off));
  }
  if ((tid & 63) == 0) {
    redA[tid >> 6] = lmin;
    redB[tid >> 6] = lmax;
  }
  __syncthreads();
  const float minpos = fminf(fminf(redA[0], redA[1]), fminf(redA[2], redA[3]));
  const float maxneg = fmaxf(fmaxf(redB[0], redB[1]), fmaxf(redB[2], redB[3]));
  __syncthreads();

  float pc = 0.f, nc = 0.f;
#pragma unroll
  for (int q = 0; q < 8; ++q) {
    const float* sp = (const float*)&sv[q];
#pragma unroll
    for (int e = 0; e < 4; ++e) {
      const bool same = (mmask >> (q * 4 + e)) & 1u;
      const float s = sp[e];
      if (same) {
        if (s < 1.0f && (s - 0.1f) < maxneg) pc += 1.f;
      } else {
        if ((s + 0.1f) > minpos) nc += 1.f;
      }
    }
  }
#pragma unroll
  for (int off = 32; off > 0; off >>= 1) {
    pc += __shfl_down(pc, off);
    nc += __shfl_down(nc, off);
  }
  if ((tid & 63) == 0) {
    redA[tid >> 6] = pc;
    redB[tid >> 6] = nc;
  }
  __syncthreads();
  const float pcnt = redA[0] + redA[1] + redA[2] + redA[3];
  const float ncnt = redB[0] + redB[1] + redB[2] + redB[3];
  const bool valid = (pcnt >= 1.f) && (ncnt >= 1.f);
  const float cp = -2.f / fmaxf(pcnt, 1.f);
  const float cn = 2.f / fmaxf(ncnt, 1.f);

#pragma unroll
  for (int q = 0; q < 8; ++q) {
    const float* sp = (const float*)&sv[q];
    float lo[4], go[4];
#pragma unroll
    for (int e = 0; e < 4; ++e) {
      const float s = sp[e];
      const bool same = (mmask >> (q * 4 + e)) & 1u;
      bool keep = same ? (s < 1.0f && (s - 0.1f) < maxneg)
                       : ((s + 0.1f) > minpos);
      keep = keep && valid;
      const float z = same ? fmaf(-2.f, s, 1.f) : fmaf(40.f, s, -20.f);
      const float ez = __expf(z);
      const float d = 1.f + ez;
      const float ll = __logf(d);
      const float sig = __fdividef(ez, d);
      const float lv = same ? ll : 0.05f * ll;
      const float gv = (same ? cp : cn) * sig;
      lo[e] = keep ? lv : 0.f;
      go[e] = keep ? gv : 0.f;
    }
    const size_t a = rowOff + (size_t)(tid * 4 + q * 1024);
    *(float4*)&lossG[a] = make_float4(lo[0], lo[1], lo[2], lo[3]);
    *(float4*)&gradG[a] = make_float4(go[0], go[1], go[2], go[3]);
  }
}

extern "C" void kernel_launch(void* const* d_in, const int* in_sizes, int n_in,
                              void* d_out, int out_size, void* d_ws,
                              size_t ws_size, hipStream_t stream) {
  const float* X = (const float*)d_in[0];
  const int* tgt = (const int*)d_in[1];
  float* out = (float*)d_out;
  float* lossG = out;                    // first N*N: pair_loss
  float* gradG = out + (size_t)NN * NN;  // second N*N: pair_grad (sim scratch)

  // Xc (4 MiB f16) lives in the loss half of d_out: only read by sim_mfma,
  // and row_kernel overwrites lossG strictly after sim is materialized.
  _Float16* Xc = (_Float16*)lossG;

  hipLaunchKernelGGL(prep_kernel, dim3(NN * DD / (256 * 8)), dim3(256), 0,
                     stream, X, Xc);
  hipLaunchKernelGGL(sim_mfma_kernel, dim3(64 * 64), dim3(512), 0, stream, Xc,
                     gradG);
  hipLaunchKernelGGL(row_kernel, dim3(NN), dim3(256), 0, stream, gradG, tgt,
                     lossG, gradG);
}

// Round 5
// 235.450 us; speedup vs baseline: 2.8707x; 1.0174x over previous
//
#include <hip/hip_runtime.h>
#include <hip/hip_fp16.h>

#define NN 8192
#define DD 128

typedef _Float16 f16x8 __attribute__((ext_vector_type(8)));
typedef float f32x4 __attribute__((ext_vector_type(4)));

// ---------------------------------------------------------------------------
// prep: Xc[row][0..127] = f16(x), Xc[row][128..255] = f16(x - f16(x)).
// sim = Xc @ Xc^T equals x@x^T up to ~1e-6.
// ---------------------------------------------------------------------------
__global__ __launch_bounds__(256) void prep_kernel(const float* __restrict__ X,
                                                   _Float16* __restrict__ Xc) {
  const int t = blockIdx.x * 256 + threadIdx.x;  // 8 elems per thread
  const size_t base = (size_t)t * 8;
  const int row = (int)(base >> 7);
  const int col = (int)(base & 127);
  float4 a = *(const float4*)&X[base];
  float4 b = *(const float4*)&X[base + 4];
  const float av[8] = {a.x, a.y, a.z, a.w, b.x, b.y, b.z, b.w};
  f16x8 h, l;
#pragma unroll
  for (int e = 0; e < 8; ++e) {
    const _Float16 hh = (_Float16)av[e];
    h[e] = hh;
    l[e] = (_Float16)(av[e] - (float)hh);
  }
  *(f16x8*)&Xc[(size_t)row * 256 + col] = h;
  *(f16x8*)&Xc[(size_t)row * 256 + 128 + col] = l;
}

// ---------------------------------------------------------------------------
// sim = Xc @ Xc^T, M=N=8192, K=256 f16. 128x128 tile, 512 thr (8 waves 2x4).
// BK=64, 4 K-steps, double-buffered 16KB A/B tiles (64 KB LDS, 2 blocks/CU).
// Pipeline (T3 minimum 2-phase): issue stage(t+1) BEFORE ds_read+MFMA of t;
// one vmcnt-drain barrier per K-step.
// Swizzle: chunk ^= (row&7) within each 128B row, applied on BOTH the global
// source (inverse) and the ds_read address (rule #21). Fragment rows satisfy
// R&7 == m&7, so 16 lanes hit 8 distinct 16B slots = all 32 banks, 2-way.
// A and B fragments use the identical k-mapping -> k-permutation cancels.
// C/D layout (m89): col=lane&15, row=(lane>>4)*4+reg.
// Epilogue: LDS transpose (stride 132 f32) -> coalesced float4 stores.
// ---------------------------------------------------------------------------
__global__ __launch_bounds__(512) void sim_mfma_kernel(
    const _Float16* __restrict__ Xc, float* __restrict__ simOut) {
  __shared__ char smem[65536];  // buf b: A @ b*32768, B @ b*32768+16384

  // bijective XCD swizzle (4096 % 8 == 0)
  const int flat = blockIdx.x;
  const int swz = (flat & 7) * 512 + (flat >> 3);
  const int i0 = (swz >> 6) << 7;  // tile row
  const int j0 = (swz & 63) << 7;  // tile col

  const int tid = threadIdx.x;
  const int lane = tid & 63;
  const int w = tid >> 6;
  const int m = lane & 15, kq = lane >> 4;
  const int wr = w >> 2, wc = w & 3;  // wave rows wr*64+.., cols wc*32+..

  // Per-thread staging coords (4 chunks of 16B per K-step: 2 A + 2 B).
  // C = it*512 + tid in [0,2048): tile=C>>10, cc=C&1023, r=cc>>3, k4=cc&7.
  int s_r[4], s_k4p[4], s_dst[4], s_jrow[4];
#pragma unroll
  for (int it = 0; it < 4; ++it) {
    const int C = it * 512 + tid;
    const int tile = C >> 10;
    const int cc = C & 1023;
    const int r = cc >> 3;
    const int k4 = cc & 7;
    s_r[it] = r;
    s_k4p[it] = k4 ^ (r & 7);
    s_dst[it] = tile * 16384 + cc * 16;
    s_jrow[it] = tile;  // 0 = A (i0), 1 = B (j0)
  }

#define STAGE(ks, b)                                                          \
  {                                                                           \
    _Pragma("unroll") for (int it = 0; it < 4; ++it) {                        \
      const int row = (s_jrow[it] ? j0 : i0) + s_r[it];                       \
      const char* g = (const char*)Xc + ((size_t)row << 9) + (ks)*128 +       \
                      (s_k4p[it] << 4);                                       \
      __builtin_amdgcn_global_load_lds(                                       \
          (const __attribute__((address_space(1))) void*)g,                   \
          (__attribute__((address_space(3))) void*)(smem + (b)*32768 +        \
                                                    s_dst[it]),               \
          16, 0, 0);                                                          \
    }                                                                         \
  }

  f32x4 acc[4][2] = {};

  STAGE(0, 0);
  __syncthreads();

#pragma unroll
  for (int ks = 0; ks < 4; ++ks) {
    const int b = ks & 1;
    if (ks < 3) STAGE(ks + 1, b ^ 1);  // prefetch while computing
    const _Float16* As = (const _Float16*)(smem + b * 32768);
    const _Float16* Bs = (const _Float16*)(smem + b * 32768 + 16384);
#pragma unroll
    for (int t = 0; t < 2; ++t) {
      const int ch = (t * 4 + kq) ^ (m & 7);  // swizzled chunk
      f16x8 af[4], bf[2];
#pragma unroll
      for (int f = 0; f < 4; ++f) {
        const int R = wr * 64 + f * 16 + m;  // R&7 == m&7
        af[f] = *(const f16x8*)(As + R * 64 + ch * 8);
      }
#pragma unroll
      for (int g = 0; g < 2; ++g) {
        const int R = wc * 32 + g * 16 + m;
        bf[g] = *(const f16x8*)(Bs + R * 64 + ch * 8);
      }
#pragma unroll
      for (int f = 0; f < 4; ++f)
#pragma unroll
        for (int g = 0; g < 2; ++g)
          acc[f][g] = __builtin_amdgcn_mfma_f32_16x16x32_f16(af[f], bf[g],
                                                             acc[f][g], 0, 0, 0);
    }
    __syncthreads();  // drains vmcnt (prefetch landed) + lgkm before swap
  }
#undef STAGE

  // Epilogue: half-tile (64 rows) at a time through LDS, float4 stores.
  float* Tr = (float*)smem;  // 64 x 132 f32 = 33.8 KB
#pragma unroll
  for (int ph = 0; ph < 2; ++ph) {
    if (ph) __syncthreads();
    if (wr == ph) {
#pragma unroll
      for (int f = 0; f < 4; ++f)
#pragma unroll
        for (int g = 0; g < 2; ++g)
#pragma unroll
          for (int rg = 0; rg < 4; ++rg)
            Tr[(f * 16 + kq * 4 + rg) * 132 + wc * 32 + g * 16 + m] =
                acc[f][g][rg];
    }
    __syncthreads();
#pragma unroll
    for (int it = 0; it < 4; ++it) {
      const int F = it * 512 + tid;
      const int row = F >> 5;
      const int c4 = (F & 31) * 4;
      const float4 v = *(const float4*)&Tr[row * 132 + c4];
      *(float4*)&simOut[(size_t)(i0 + ph * 64 + row) * NN + j0 + c4] = v;
    }
  }
}

// ---------------------------------------------------------------------------
// row_kernel: one block per row; 32 sim values per thread in registers,
// native transcendentals, branchless epilogue. (at HBM roofline, unchanged)
// ---------------------------------------------------------------------------
__global__ __launch_bounds__(256) void row_kernel(const float* simG,
                                                  const int* __restrict__ tgt,
                                                  float* lossG,
                                                  float* gradG) {
  __shared__ unsigned char tg[NN];
  __shared__ float redA[4];
  __shared__ float redB[4];
  const int i = blockIdx.x;
  const int tid = threadIdx.x;
  const size_t rowOff = (size_t)i * NN;

  for (int b = tid * 4; b < NN; b += 1024) {
    int4 t4 = *(const int4*)&tgt[b];
    tg[b + 0] = (unsigned char)t4.x;
    tg[b + 1] = (unsigned char)t4.y;
    tg[b + 2] = (unsigned char)t4.z;
    tg[b + 3] = (unsigned char)t4.w;
  }
  const unsigned char tci = (unsigned char)tgt[i];

  float4 sv[8];
#pragma unroll
  for (int q = 0; q < 8; ++q)
    sv[q] = *(const float4*)&simG[rowOff + (size_t)(tid * 4 + q * 1024)];
  __syncthreads();

  unsigned mmask = 0;
  float lmin = 1e30f, lmax = -1e30f;
#pragma unroll
  for (int q = 0; q < 8; ++q) {
    uchar4 t4 = *(const uchar4*)&tg[tid * 4 + q * 1024];
    const unsigned char tt[4] = {t4.x, t4.y, t4.z, t4.w};
    const float* sp = (const float*)&sv[q];
#pragma unroll
    for (int e = 0; e < 4; ++e) {
      const bool same = (tt[e] == tci);
      const float s = sp[e];
      if (same) {
        mmask |= (1u << (q * 4 + e));
        if (s < 1.0f) lmin = fminf(lmin, s);
      } else {
        lmax = fmaxf(lmax, s);
      }
    }
  }
#pragma unroll
  for (int off = 32; off > 0; off >>= 1) {
    lmin = fminf(lmin, __shfl_down(lmin, off));
    lmax = fmaxf(lmax, __shfl_down(lmax, off));
  }
  if ((tid & 63) == 0) {
    redA[tid >> 6] = lmin;
    redB[tid >> 6] = lmax;
  }
  __syncthreads();
  const float minpos = fminf(fminf(redA[0], redA[1]), fminf(redA[2], redA[3]));
  const float maxneg = fmaxf(fmaxf(redB[0], redB[1]), fmaxf(redB[2], redB[3]));
  __syncthreads();

  float pc = 0.f, nc = 0.f;
#pragma unroll
  for (int q = 0; q < 8; ++q) {
    const float* sp = (const float*)&sv[q];
#pragma unroll
    for (int e = 0; e < 4; ++e) {
      const bool same = (mmask >> (q * 4 + e)) & 1u;
      const float s = sp[e];
      if (same) {
        if (s < 1.0f && (s - 0.1f) < maxneg) pc += 1.f;
      } else {
        if ((s + 0.1f) > minpos) nc += 1.f;
      }
    }
  }
#pragma unroll
  for (int off = 32; off > 0; off >>= 1) {
    pc += __shfl_down(pc, off);
    nc += __shfl_down(nc, off);
  }
  if ((tid & 63) == 0) {
    redA[tid >> 6] = pc;
    redB[tid >> 6] = nc;
  }
  __syncthreads();
  const float pcnt = redA[0] + redA[1] + redA[2] + redA[3];
  const float ncnt = redB[0] + redB[1] + redB[2] + redB[3];
  const bool valid = (pcnt >= 1.f) && (ncnt >= 1.f);
  const float cp = -2.f / fmaxf(pcnt, 1.f);
  const float cn = 2.f / fmaxf(ncnt, 1.f);

#pragma unroll
  for (int q = 0; q < 8; ++q) {
    const float* sp = (const float*)&sv[q];
    float lo[4], go[4];
#pragma unroll
    for (int e = 0; e < 4; ++e) {
      const float s = sp[e];
      const bool same = (mmask >> (q * 4 + e)) & 1u;
      bool keep = same ? (s < 1.0f && (s - 0.1f) < maxneg)
                       : ((s + 0.1f) > minpos);
      keep = keep && valid;
      const float z = same ? fmaf(-2.f, s, 1.f) : fmaf(40.f, s, -20.f);
      const float ez = __expf(z);
      const float d = 1.f + ez;
      const float ll = __logf(d);
      const float sig = __fdividef(ez, d);
      const float lv = same ? ll : 0.05f * ll;
      const float gv = (same ? cp : cn) * sig;
      lo[e] = keep ? lv : 0.f;
      go[e] = keep ? gv : 0.f;
    }
    const size_t a = rowOff + (size_t)(tid * 4 + q * 1024);
    *(float4*)&lossG[a] = make_float4(lo[0], lo[1], lo[2], lo[3]);
    *(float4*)&gradG[a] = make_float4(go[0], go[1], go[2], go[3]);
  }
}

extern "C" void kernel_launch(void* const* d_in, const int* in_sizes, int n_in,
                              void* d_out, int out_size, void* d_ws,
                              size_t ws_size, hipStream_t stream) {
  const float* X = (const float*)d_in[0];
  const int* tgt = (const int*)d_in[1];
  float* out = (float*)d_out;
  float* lossG = out;                    // first N*N: pair_loss
  float* gradG = out + (size_t)NN * NN;  // second N*N: pair_grad (sim scratch)

  // Xc (4 MiB f16) lives in the loss half of d_out: only read by sim_mfma,
  // and row_kernel overwrites lossG strictly after sim is materialized.
  _Float16* Xc = (_Float16*)lossG;

  hipLaunchKernelGGL(prep_kernel, dim3(NN * DD / (256 * 8)), dim3(256), 0,
                     stream, X, Xc);
  hipLaunchKernelGGL(sim_mfma_kernel, dim3(64 * 64), dim3(512), 0, stream, Xc,
                     gradG);
  hipLaunchKernelGGL(row_kernel, dim3(NN), dim3(256), 0, stream, gradG, tgt,
                     lossG, gradG);
}

// Round 7
// 209.833 us; speedup vs baseline: 3.2212x; 1.1221x over previous
//
#include <hip/hip_runtime.h>
#include <hip/hip_fp16.h>

#define NN 8192
#define DD 128

typedef _Float16 f16x8 __attribute__((ext_vector_type(8)));
typedef float f32x4 __attribute__((ext_vector_type(4)));

// ---------------------------------------------------------------------------
// prep: Xc[row][0..127] = f16(x), Xc[row][128..255] = f16(x - f16(x)).
// sim = Xc @ Xc^T equals x@x^T up to ~1e-6.
// ---------------------------------------------------------------------------
__global__ __launch_bounds__(256) void prep_kernel(const float* __restrict__ X,
                                                   _Float16* __restrict__ Xc) {
  const int t = blockIdx.x * 256 + threadIdx.x;  // 8 elems per thread
  const size_t base = (size_t)t * 8;
  const int row = (int)(base >> 7);
  const int col = (int)(base & 127);
  float4 a = *(const float4*)&X[base];
  float4 b = *(const float4*)&X[base + 4];
  const float av[8] = {a.x, a.y, a.z, a.w, b.x, b.y, b.z, b.w};
  f16x8 h, l;
#pragma unroll
  for (int e = 0; e < 8; ++e) {
    const _Float16 hh = (_Float16)av[e];
    h[e] = hh;
    l[e] = (_Float16)(av[e] - (float)hh);
  }
  *(f16x8*)&Xc[(size_t)row * 256 + col] = h;
  *(f16x8*)&Xc[(size_t)row * 256 + 128 + col] = l;
}

// ---------------------------------------------------------------------------
// sim = Xc @ Xc^T, M=N=8192, K=256 f16. 128x128 tile, 512 thr (8 waves 2x4,
// wave tile 64x32). BK=32, 8 K-steps, TRIPLE-buffered 16KB A+B tiles
// (48 KB LDS; Tr epilogue buffer unions into the same 48 KB).
// T4 counted-vmcnt pipeline: prefetch distance 2; per step
//   STAGE(ks+2) ; compute(ks) ; s_waitcnt vmcnt(2) ; s_barrier ; sched_barrier
// so stage(ks+1) has a full K-step of latency cover; vmcnt never drains to 0
// in the main loop. Triple buffering => no LDS WAR hazard inside the loop.
// Swizzle: 64B rows, 4 chunks, chunk ^= row&3 on BOTH global source (inverse)
// and ds_read (rule #21). Fragment rows satisfy R&3 == m&3 -> uniform banks.
// A and B fragments use identical k-mapping -> k-permutation cancels in A.B^T.
// C/D layout (m89): col=lane&15, row=(lane>>4)*4+reg.
// ---------------------------------------------------------------------------
__global__ __launch_bounds__(512, 6) void sim_mfma_kernel(
    const _Float16* __restrict__ Xc, float* __restrict__ simOut) {
  __shared__ char smem[49152];  // buf b @ b*16384 (A 8KB, B 8KB); Tr unions

  // bijective XCD swizzle (4096 % 8 == 0)
  const int flat = blockIdx.x;
  const int swz = (flat & 7) * 512 + (flat >> 3);
  const int i0 = (swz >> 6) << 7;  // tile row
  const int j0 = (swz & 63) << 7;  // tile col

  const int tid = threadIdx.x;
  const int lane = tid & 63;
  const int w = tid >> 6;
  const int m = lane & 15, kq = lane >> 4;
  const int wr = w >> 2, wc = w & 3;  // wave rows wr*64+.., cols wc*32+..

  // Staging coords: 2 chunks of 16B per thread per K-step (A+B = 16 KB).
  // C = it*512 + tid in [0,1024): tile=C>>9, cc=C&511, r=cc>>2, k4=cc&3.
  int sg_off[2];  // global byte offset within a row-block, pre-swizzled
  int sd_off[2];  // LDS byte offset within a buffer
  int sg_row[2];  // global row (absolute)
#pragma unroll
  for (int it = 0; it < 2; ++it) {
    const int C = it * 512 + tid;
    const int tile = C >> 9;
    const int cc = C & 511;
    const int r = cc >> 2;
    const int k4 = cc & 3;
    const int k4p = k4 ^ (r & 3);  // inverse swizzle on global source
    sg_row[it] = (tile ? j0 : i0) + r;
    sg_off[it] = k4p << 4;
    sd_off[it] = tile * 8192 + cc * 16;
  }

#define STAGE(ks, b)                                                         \
  {                                                                          \
    _Pragma("unroll") for (int it = 0; it < 2; ++it) {                       \
      const char* g = (const char*)Xc + ((size_t)sg_row[it] << 9) +          \
                      (ks)*64 + sg_off[it];                                  \
      __builtin_amdgcn_global_load_lds(                                      \
          (const __attribute__((address_space(1))) void*)g,                  \
          (__attribute__((address_space(3))) void*)(smem + (b)*16384 +       \
                                                    sd_off[it]),             \
          16, 0, 0);                                                         \
    }                                                                        \
  }

  f32x4 acc[4][2] = {};

  // Prologue: stage(0)->buf0, stage(1)->buf1; wait stage(0); barrier.
  STAGE(0, 0);
  STAGE(1, 1);
  asm volatile("s_waitcnt vmcnt(2)" ::: "memory");
  __builtin_amdgcn_s_barrier();
  __builtin_amdgcn_sched_barrier(0);

#pragma unroll
  for (int ks = 0; ks < 8; ++ks) {
    const int b = ks % 3;
    if (ks < 6) STAGE(ks + 2, (ks + 2) % 3);
    const _Float16* As = (const _Float16*)(smem + b * 16384);
    const _Float16* Bs = (const _Float16*)(smem + b * 16384 + 8192);
    f16x8 af[4], bf[2];
#pragma unroll
    for (int f = 0; f < 4; ++f) {
      const int R = wr * 64 + f * 16 + m;  // R&3 == m&3
      af[f] = *(const f16x8*)(As + R * 32 + ((kq ^ (R & 3)) << 3));
    }
#pragma unroll
    for (int g = 0; g < 2; ++g) {
      const int R = wc * 32 + g * 16 + m;
      bf[g] = *(const f16x8*)(Bs + R * 32 + ((kq ^ (R & 3)) << 3));
    }
#pragma unroll
    for (int f = 0; f < 4; ++f)
#pragma unroll
      for (int g = 0; g < 2; ++g)
        acc[f][g] = __builtin_amdgcn_mfma_f32_16x16x32_f16(af[f], bf[g],
                                                           acc[f][g], 0, 0, 0);
    if (ks < 7) {
      if (ks < 6) {
        asm volatile("s_waitcnt vmcnt(2)" ::: "memory");
      } else {
        asm volatile("s_waitcnt vmcnt(0)" ::: "memory");
      }
      __builtin_amdgcn_s_barrier();
      __builtin_amdgcn_sched_barrier(0);
    }
  }
#undef STAGE
  __syncthreads();  // full drain before LDS reuse as Tr

  // Epilogue: half-tile (64 rows) at a time through LDS, float4 stores.
  float* Tr = (float*)smem;  // 64 x 132 f32 = 33792 B
#pragma unroll
  for (int ph = 0; ph < 2; ++ph) {
    if (ph) __syncthreads();
    if (wr == ph) {
#pragma unroll
      for (int f = 0; f < 4; ++f)
#pragma unroll
        for (int g = 0; g < 2; ++g)
#pragma unroll
          for (int rg = 0; rg < 4; ++rg)
            Tr[(f * 16 + kq * 4 + rg) * 132 + wc * 32 + g * 16 + m] =
                acc[f][g][rg];
    }
    __syncthreads();
#pragma unroll
    for (int it = 0; it < 4; ++it) {
      const int F = it * 512 + tid;
      const int row = F >> 5;
      const int c4 = (F & 31) * 4;
      const float4 v = *(const float4*)&Tr[row * 132 + c4];
      *(float4*)&simOut[(size_t)(i0 + ph * 64 + row) * NN + j0 + c4] = v;
    }
  }
}

// ---------------------------------------------------------------------------
// row_kernel: one block per row; 32 sim values per thread in registers,
// native transcendentals, branchless epilogue, non-temporal output stores.
// ---------------------------------------------------------------------------
__global__ __launch_bounds__(256) void row_kernel(const float* simG,
                                                  const int* __restrict__ tgt,
                                                  float* lossG,
                                                  float* gradG) {
  __shared__ unsigned char tg[NN];
  __shared__ float redA[4];
  __shared__ float redB[4];
  const int i = blockIdx.x;
  const int tid = threadIdx.x;
  const size_t rowOff = (size_t)i * NN;

  for (int b = tid * 4; b < NN; b += 1024) {
    int4 t4 = *(const int4*)&tgt[b];
    tg[b + 0] = (unsigned char)t4.x;
    tg[b + 1] = (unsigned char)t4.y;
    tg[b + 2] = (unsigned char)t4.z;
    tg[b + 3] = (unsigned char)t4.w;
  }
  const unsigned char tci = (unsigned char)tgt[i];

  float4 sv[8];
#pragma unroll
  for (int q = 0; q < 8; ++q)
    sv[q] = *(const float4*)&simG[rowOff + (size_t)(tid * 4 + q * 1024)];
  __syncthreads();

  unsigned mmask = 0;
  float lmin = 1e30f, lmax = -1e30f;
#pragma unroll
  for (int q = 0; q < 8; ++q) {
    uchar4 t4 = *(const uchar4*)&tg[tid * 4 + q * 1024];
    const unsigned char tt[4] = {t4.x, t4.y, t4.z, t4.w};
    const float* sp = (const float*)&sv[q];
#pragma unroll
    for (int e = 0; e < 4; ++e) {
      const bool same = (tt[e] == tci);
      const float s = sp[e];
      if (same) {
        mmask |= (1u << (q * 4 + e));
        if (s < 1.0f) lmin = fminf(lmin, s);
      } else {
        lmax = fmaxf(lmax, s);
      }
    }
  }
#pragma unroll
  for (int off = 32; off > 0; off >>= 1) {
    lmin = fminf(lmin, __shfl_down(lmin, off));
    lmax = fmaxf(lmax, __shfl_down(lmax, off));
  }
  if ((tid & 63) == 0) {
    redA[tid >> 6] = lmin;
    redB[tid >> 6] = lmax;
  }
  __syncthreads();
  const float minpos = fminf(fminf(redA[0], redA[1]), fminf(redA[2], redA[3]));
  const float maxneg = fmaxf(fmaxf(redB[0], redB[1]), fmaxf(redB[2], redB[3]));
  __syncthreads();

  float pc = 0.f, nc = 0.f;
#pragma unroll
  for (int q = 0; q < 8; ++q) {
    const float* sp = (const float*)&sv[q];
#pragma unroll
    for (int e = 0; e < 4; ++e) {
      const bool same = (mmask >> (q * 4 + e)) & 1u;
      const float s = sp[e];
      if (same) {
        if (s < 1.0f && (s - 0.1f) < maxneg) pc += 1.f;
      } else {
        if ((s + 0.1f) > minpos) nc += 1.f;
      }
    }
  }
#pragma unroll
  for (int off = 32; off > 0; off >>= 1) {
    pc += __shfl_down(pc, off);
    nc += __shfl_down(nc, off);
  }
  if ((tid & 63) == 0) {
    redA[tid >> 6] = pc;
    redB[tid >> 6] = nc;
  }
  __syncthreads();
  const float pcnt = redA[0] + redA[1] + redA[2] + redA[3];
  const float ncnt = redB[0] + redB[1] + redB[2] + redB[3];
  const bool valid = (pcnt >= 1.f) && (ncnt >= 1.f);
  const float cp = -2.f / fmaxf(pcnt, 1.f);
  const float cn = 2.f / fmaxf(ncnt, 1.f);

#pragma unroll
  for (int q = 0; q < 8; ++q) {
    const float* sp = (const float*)&sv[q];
    float lo[4], go[4];
#pragma unroll
    for (int e = 0; e < 4; ++e) {
      const float s = sp[e];
      const bool same = (mmask >> (q * 4 + e)) & 1u;
      bool keep = same ? (s < 1.0f && (s - 0.1f) < maxneg)
                       : ((s + 0.1f) > minpos);
      keep = keep && valid;
      const float z = same ? fmaf(-2.f, s, 1.f) : fmaf(40.f, s, -20.f);
      const float ez = __expf(z);
      const float d = 1.f + ez;
      const float ll = __logf(d);
      const float sig = __fdividef(ez, d);
      const float lv = same ? ll : 0.05f * ll;
      const float gv = (same ? cp : cn) * sig;
      lo[e] = keep ? lv : 0.f;
      go[e] = keep ? gv : 0.f;
    }
    const size_t a = rowOff + (size_t)(tid * 4 + q * 1024);
    f32x4 lv4 = {lo[0], lo[1], lo[2], lo[3]};
    f32x4 gv4 = {go[0], go[1], go[2], go[3]};
    __builtin_nontemporal_store(lv4, (f32x4*)&lossG[a]);
    __builtin_nontemporal_store(gv4, (f32x4*)&gradG[a]);
  }
}

extern "C" void kernel_launch(void* const* d_in, const int* in_sizes, int n_in,
                              void* d_out, int out_size, void* d_ws,
                              size_t ws_size, hipStream_t stream) {
  const float* X = (const float*)d_in[0];
  const int* tgt = (const int*)d_in[1];
  float* out = (float*)d_out;
  float* lossG = out;                    // first N*N: pair_loss
  float* gradG = out + (size_t)NN * NN;  // second N*N: pair_grad (sim scratch)

  // Xc (4 MiB f16) lives in the loss half of d_out: only read by sim_mfma,
  // and row_kernel overwrites lossG strictly after sim is materialized.
  _Float16* Xc = (_Float16*)lossG;

  hipLaunchKernelGGL(prep_kernel, dim3(NN * DD / (256 * 8)), dim3(256), 0,
                     stream, X, Xc);
  hipLaunchKernelGGL(sim_mfma_kernel, dim3(64 * 64), dim3(512), 0, stream, Xc,
                     gradG);
  hipLaunchKernelGGL(row_kernel, dim3(NN), dim3(256), 0, stream, gradG, tgt,
                     lossG, gradG);
}

// Round 10
// 209.314 us; speedup vs baseline: 3.2291x; 1.0025x over previous
//
#include <hip/hip_runtime.h>
#include <hip/hip_fp16.h>

#define NN 8192
#define DD 128

typedef _Float16 f16x8 __attribute__((ext_vector_type(8)));
typedef float f32x4 __attribute__((ext_vector_type(4)));

// ---------------------------------------------------------------------------
// prep: Xc[row][0..127] = f16(x), Xc[row][128..255] = f16(x - f16(x)).
// sim = Xc @ Xc^T equals x@x^T up to ~1e-6.
// ---------------------------------------------------------------------------
__global__ __launch_bounds__(256) void prep_kernel(const float* __restrict__ X,
                                                   _Float16* __restrict__ Xc) {
  const int t = blockIdx.x * 256 + threadIdx.x;  // 8 elems per thread
  const size_t base = (size_t)t * 8;
  const int row = (int)(base >> 7);
  const int col = (int)(base & 127);
  float4 a = *(const float4*)&X[base];
  float4 b = *(const float4*)&X[base + 4];
  const float av[8] = {a.x, a.y, a.z, a.w, b.x, b.y, b.z, b.w};
  f16x8 h, l;
#pragma unroll
  for (int e = 0; e < 8; ++e) {
    const _Float16 hh = (_Float16)av[e];
    h[e] = hh;
    l[e] = (_Float16)(av[e] - (float)hh);
  }
  *(f16x8*)&Xc[(size_t)row * 256 + col] = h;
  *(f16x8*)&Xc[(size_t)row * 256 + 128 + col] = l;
}

// ---------------------------------------------------------------------------
// sim = Xc @ Xc^T, M=N=8192, K=256 f16. 128x128 tile, 256 thr (4 waves 2x2,
// wave tile 64x64 -> 16 B LDS-read/output, 8 ds_read_b128 : 16 MFMA per
// K-step). BK=32, 8 K-steps, DOUBLE-buffered 16KB (A 8KB + B 8KB) buffers =
// 32 KB LDS -> 4 blocks/CU (__launch_bounds__(256,4)); block-level overlap
// hides the per-step drain + write epilogue.
// DETERMINISM RULE (round-9 lesson): custom counted-vmcnt schedules raced
// timing-dependently (tripwire). ALL sync here is plain __syncthreads()
// (vmcnt(0)+lgkmcnt(0)+barrier). Schedule = R5's proven shape:
//   STAGE(0); sync; { STAGE(ks+1); compute(ks); sync; }  -- prefetch gets the
// compute phase of in-flight time, drained at the step-end sync.
// Swizzle: 64B rows, 4 chunks, chunk ^= row&3 on BOTH global source (inverse)
// and ds_read (rule #21). Fragment rows satisfy R&3 == m&3.
// A and B fragments use identical k-mapping -> k-permutation cancels in A.B^T.
// C/D layout (m89): col=lane&15, row=(lane>>4)*4+reg.
// Epilogue: Tr 64x128 f32 = exactly 32 KB (unions both dead buffers).
// ---------------------------------------------------------------------------
__global__ __launch_bounds__(256, 4) void sim_mfma_kernel(
    const _Float16* __restrict__ Xc, float* __restrict__ simOut) {
  __shared__ char smem[32768];  // buf b @ b*16384 (A 8KB, B 8KB); Tr unions

  // bijective XCD swizzle (4096 % 8 == 0)
  const int flat = blockIdx.x;
  const int swz = (flat & 7) * 512 + (flat >> 3);
  const int i0 = (swz >> 6) << 7;  // tile row
  const int j0 = (swz & 63) << 7;  // tile col

  const int tid = threadIdx.x;
  const int lane = tid & 63;
  const int w = tid >> 6;
  const int m = lane & 15, kq = lane >> 4;
  const int wr = w >> 1, wc = w & 1;  // wave rows wr*64+.., cols wc*64+..

  // Staging coords: 4 chunks of 16B per thread per K-step (A+B = 16 KB).
  // C = it*256 + tid in [0,1024): tile=C>>9, cc=C&511, r=cc>>2, k4=cc&3.
  int sg_off[4];  // global byte offset within a row, pre-swizzled
  int sd_off[4];  // LDS byte offset within a buffer
  int sg_row[4];  // global row (absolute)
#pragma unroll
  for (int it = 0; it < 4; ++it) {
    const int C = it * 256 + tid;
    const int tile = C >> 9;
    const int cc = C & 511;
    const int r = cc >> 2;
    const int k4 = cc & 3;
    const int k4p = k4 ^ (r & 3);  // inverse swizzle on global source
    sg_row[it] = (tile ? j0 : i0) + r;
    sg_off[it] = k4p << 4;
    sd_off[it] = tile * 8192 + cc * 16;
  }

#define STAGE(ks, b)                                                         \
  {                                                                          \
    _Pragma("unroll") for (int it = 0; it < 4; ++it) {                       \
      const char* g = (const char*)Xc + ((size_t)sg_row[it] << 9) +          \
                      (ks)*64 + sg_off[it];                                  \
      __builtin_amdgcn_global_load_lds(                                      \
          (const __attribute__((address_space(1))) void*)g,                  \
          (__attribute__((address_space(3))) void*)(smem + (b)*16384 +       \
                                                    sd_off[it]),             \
          16, 0, 0);                                                         \
    }                                                                        \
  }

  f32x4 acc[4][4] = {};

  STAGE(0, 0);
  __syncthreads();  // stage(0) landed (vmcnt 0 + barrier)

#pragma unroll
  for (int ks = 0; ks < 8; ++ks) {
    const int b = ks & 1;
    if (ks < 7) STAGE(ks + 1, b ^ 1);  // prefetch; drained at step-end sync
    const _Float16* As = (const _Float16*)(smem + b * 16384);
    const _Float16* Bs = (const _Float16*)(smem + b * 16384 + 8192);
    f16x8 af[4], bf[4];
#pragma unroll
    for (int f = 0; f < 4; ++f) {
      const int R = wr * 64 + f * 16 + m;  // R&3 == m&3
      af[f] = *(const f16x8*)(As + R * 32 + ((kq ^ (R & 3)) << 3));
    }
#pragma unroll
    for (int g = 0; g < 4; ++g) {
      const int R = wc * 64 + g * 16 + m;
      bf[g] = *(const f16x8*)(Bs + R * 32 + ((kq ^ (R & 3)) << 3));
    }
#pragma unroll
    for (int f = 0; f < 4; ++f)
#pragma unroll
      for (int g = 0; g < 4; ++g)
        acc[f][g] = __builtin_amdgcn_mfma_f32_16x16x32_f16(af[f], bf[g],
                                                           acc[f][g], 0, 0, 0);
    __syncthreads();  // drains vmcnt+lgkm; next-step buffer ready, WAR safe
  }
#undef STAGE

  // Epilogue: half-tile (64 rows) at a time through LDS, float4 stores.
  // Tr = 64 x 128 f32 = exactly 32 KB (buffers are dead after the loop-end
  // sync). Stride 128 f32: write phase is 4-way bank-aliased (cheap, short);
  // read phase conflict-free (32 lanes read 512B contiguous rows).
  float* Tr = (float*)smem;
#pragma unroll
  for (int ph = 0; ph < 2; ++ph) {
    if (ph) __syncthreads();
    if (wr == ph) {  // 2 waves own this 64-row half
#pragma unroll
      for (int f = 0; f < 4; ++f)
#pragma unroll
        for (int g = 0; g < 4; ++g)
#pragma unroll
          for (int rg = 0; rg < 4; ++rg)
            Tr[(f * 16 + kq * 4 + rg) * 128 + wc * 64 + g * 16 + m] =
                acc[f][g][rg];
    }
    __syncthreads();
#pragma unroll
    for (int it = 0; it < 8; ++it) {
      const int F = it * 256 + tid;
      const int row = F >> 5;
      const int c4 = (F & 31) * 4;
      const float4 v = *(const float4*)&Tr[row * 128 + c4];
      *(float4*)&simOut[(size_t)(i0 + ph * 64 + row) * NN + j0 + c4] = v;
    }
  }
}

// ---------------------------------------------------------------------------
// row_kernel: one block per row; 32 sim values per thread in registers,
// native transcendentals, branchless epilogue, non-temporal output stores.
// ---------------------------------------------------------------------------
__global__ __launch_bounds__(256) void row_kernel(const float* simG,
                                                  const int* __restrict__ tgt,
                                                  float* lossG,
                                                  float* gradG) {
  __shared__ unsigned char tg[NN];
  __shared__ float redA[4];
  __shared__ float redB[4];
  const int i = blockIdx.x;
  const int tid = threadIdx.x;
  const size_t rowOff = (size_t)i * NN;

  for (int b = tid * 4; b < NN; b += 1024) {
    int4 t4 = *(const int4*)&tgt[b];
    tg[b + 0] = (unsigned char)t4.x;
    tg[b + 1] = (unsigned char)t4.y;
    tg[b + 2] = (unsigned char)t4.z;
    tg[b + 3] = (unsigned char)t4.w;
  }
  const unsigned char tci = (unsigned char)tgt[i];

  float4 sv[8];
#pragma unroll
  for (int q = 0; q < 8; ++q)
    sv[q] = *(const float4*)&simG[rowOff + (size_t)(tid * 4 + q * 1024)];
  __syncthreads();

  unsigned mmask = 0;
  float lmin = 1e30f, lmax = -1e30f;
#pragma unroll
  for (int q = 0; q < 8; ++q) {
    uchar4 t4 = *(const uchar4*)&tg[tid * 4 + q * 1024];
    const unsigned char tt[4] = {t4.x, t4.y, t4.z, t4.w};
    const float* sp = (const float*)&sv[q];
#pragma unroll
    for (int e = 0; e < 4; ++e) {
      const bool same = (tt[e] == tci);
      const float s = sp[e];
      if (same) {
        mmask |= (1u << (q * 4 + e));
        if (s < 1.0f) lmin = fminf(lmin, s);
      } else {
        lmax = fmaxf(lmax, s);
      }
    }
  }
#pragma unroll
  for (int off = 32; off > 0; off >>= 1) {
    lmin = fminf(lmin, __shfl_down(lmin, off));
    lmax = fmaxf(lmax, __shfl_down(lmax, off));
  }
  if ((tid & 63) == 0) {
    redA[tid >> 6] = lmin;
    redB[tid >> 6] = lmax;
  }
  __syncthreads();
  const float minpos = fminf(fminf(redA[0], redA[1]), fminf(redA[2], redA[3]));
  const float maxneg = fmaxf(fmaxf(redB[0], redB[1]), fmaxf(redB[2], redB[3]));
  __syncthreads();

  float pc = 0.f, nc = 0.f;
#pragma unroll
  for (int q = 0; q < 8; ++q) {
    const float* sp = (const float*)&sv[q];
#pragma unroll
    for (int e = 0; e < 4; ++e) {
      const bool same = (mmask >> (q * 4 + e)) & 1u;
      const float s = sp[e];
      if (same) {
        if (s < 1.0f && (s - 0.1f) < maxneg) pc += 1.f;
      } else {
        if ((s + 0.1f) > minpos) nc += 1.f;
      }
    }
  }
#pragma unroll
  for (int off = 32; off > 0; off >>= 1) {
    pc += __shfl_down(pc, off);
    nc += __shfl_down(nc, off);
  }
  if ((tid & 63) == 0) {
    redA[tid >> 6] = pc;
    redB[tid >> 6] = nc;
  }
  __syncthreads();
  const float pcnt = redA[0] + redA[1] + redA[2] + redA[3];
  const float ncnt = redB[0] + redB[1] + redB[2] + redB[3];
  const bool valid = (pcnt >= 1.f) && (ncnt >= 1.f);
  const float cp = -2.f / fmaxf(pcnt, 1.f);
  const float cn = 2.f / fmaxf(ncnt, 1.f);

#pragma unroll
  for (int q = 0; q < 8; ++q) {
    const float* sp = (const float*)&sv[q];
    float lo[4], go[4];
#pragma unroll
    for (int e = 0; e < 4; ++e) {
      const float s = sp[e];
      const bool same = (mmask >> (q * 4 + e)) & 1u;
      bool keep = same ? (s < 1.0f && (s - 0.1f) < maxneg)
                       : ((s + 0.1f) > minpos);
      keep = keep && valid;
      const float z = same ? fmaf(-2.f, s, 1.f) : fmaf(40.f, s, -20.f);
      const float ez = __expf(z);
      const float d = 1.f + ez;
      const float ll = __logf(d);
      const float sig = __fdividef(ez, d);
      const float lv = same ? ll : 0.05f * ll;
      const float gv = (same ? cp : cn) * sig;
      lo[e] = keep ? lv : 0.f;
      go[e] = keep ? gv : 0.f;
    }
    const size_t a = rowOff + (size_t)(tid * 4 + q * 1024);
    f32x4 lv4 = {lo[0], lo[1], lo[2], lo[3]};
    f32x4 gv4 = {go[0], go[1], go[2], go[3]};
    __builtin_nontemporal_store(lv4, (f32x4*)&lossG[a]);
    __builtin_nontemporal_store(gv4, (f32x4*)&gradG[a]);
  }
}

extern "C" void kernel_launch(void* const* d_in, const int* in_sizes, int n_in,
                              void* d_out, int out_size, void* d_ws,
                              size_t ws_size, hipStream_t stream) {
  const float* X = (const float*)d_in[0];
  const int* tgt = (const int*)d_in[1];
  float* out = (float*)d_out;
  float* lossG = out;                    // first N*N: pair_loss
  float* gradG = out + (size_t)NN * NN;  // second N*N: pair_grad (sim scratch)

  // Xc (4 MiB f16) lives in the loss half of d_out: only read by sim_mfma,
  // and row_kernel overwrites lossG strictly after sim is materialized.
  _Float16* Xc = (_Float16*)lossG;

  hipLaunchKernelGGL(prep_kernel, dim3(NN * DD / (256 * 8)), dim3(256), 0,
                     stream, X, Xc);
  hipLaunchKernelGGL(sim_mfma_kernel, dim3(64 * 64), dim3(256), 0, stream, Xc,
                     gradG);
  hipLaunchKernelGGL(row_kernel, dim3(NN), dim3(256), 0, stream, gradG, tgt,
                     lossG, gradG);
}